// Round 10
// baseline (24.097 us; speedup 1.0000x reference)
//
#include <hip/hip_runtime.h>

// DLGN_VT v8 — K1 = v6 verbatim (best known); K2 = v6 + scalar-path g1 + paired deferred reduce.
//   K1 gates: 512 blocks x 256 thr, 8 rows/block, k-quarter split; 2-row x 6-feature
//     register tile from LDS; partials -> Pscr; combine+sigmoid -> G coalesced.
//   K2 contract: 512 blocks x 256 thr, 8 rows/block, thread=(j=t>>3, c2=t&7).
//     V in 32 float4 regs. g1 rows via WAVE-UNIFORM global loads (s_load path),
//     double-buffered gA/gB (static indices). Per bb: pA,pB computed, then their two
//     6-level shfl chains run interleaved. g2/g3 from small LDS tile.
// No atomics, no memset; G (1.5 MB) in d_ws.

#define BETA 30.0f

__device__ __forceinline__ float f4c(const float4 v, int c) {
    // compile-time c after full unroll -> folds to a register pick
    return c == 0 ? v.x : (c == 1 ? v.y : (c == 2 ? v.z : v.w));
}

// ---------------- K1: gates (v6 verbatim) ----------------
__global__ __launch_bounds__(256, 2) void gates_v8_kernel(
    const float* __restrict__ x,
    const float* __restrict__ W1,
    const float* __restrict__ W2,
    const float* __restrict__ W3,
    float* __restrict__ G)
{
    __shared__ float Wlds[96 * 132];    // 50688 B
    __shared__ float xlds[8 * 132];     //  4224 B
    __shared__ float Pscr[4][64 * 13];  // 13312 B  -> total 68224 B (2 blocks/CU)

    const int t  = threadIdx.x;
    const int b0 = blockIdx.x * 8;

#pragma unroll
    for (int r = 0; r < 13; ++r) {
        const int idx  = r * 256 + t;
        const int row  = idx >> 5;
        const int col4 = idx & 31;
        if (row < 96) {
            const float* Wr = (row < 32) ? (W1 + row * 128)
                            : (row < 64) ? (W2 + (row - 32) * 128)
                                         : (W3 + (row - 64) * 128);
            *(float4*)&Wlds[row * 132 + col4 * 4] = ((const float4*)Wr)[col4];
        } else {
            *(float4*)&xlds[(row - 96) * 132 + col4 * 4] =
                ((const float4*)(x + (size_t)(b0 + row - 96) * 128))[col4];
        }
    }
    __syncthreads();

    {
        const int ks  = t >> 6;
        const int sub = t & 63;
        const int bp  = sub & 3;
        const int fg  = sub >> 2;          // 0..15, f = fg + 16*ff
        const float* xr0 = &xlds[(2 * bp + 0) * 132];
        const float* xr1 = &xlds[(2 * bp + 1) * 132];
        const float* wb  = &Wlds[fg * 132];
        float acc0[6] = {0.f,0.f,0.f,0.f,0.f,0.f};
        float acc1[6] = {0.f,0.f,0.f,0.f,0.f,0.f};
#pragma unroll
        for (int cc = 0; cc < 8; ++cc) {
            const int c4 = (ks * 8 + cc) * 4;
            const float4 xv0 = *(const float4*)&xr0[c4];
            const float4 xv1 = *(const float4*)&xr1[c4];
#pragma unroll
            for (int ff = 0; ff < 6; ++ff) {
                const float4 wv = *(const float4*)&wb[ff * 2112 + c4];  // row fg+16ff
                acc0[ff] = fmaf(xv0.x, wv.x, acc0[ff]);
                acc0[ff] = fmaf(xv0.y, wv.y, acc0[ff]);
                acc0[ff] = fmaf(xv0.z, wv.z, acc0[ff]);
                acc0[ff] = fmaf(xv0.w, wv.w, acc0[ff]);
                acc1[ff] = fmaf(xv1.x, wv.x, acc1[ff]);
                acc1[ff] = fmaf(xv1.y, wv.y, acc1[ff]);
                acc1[ff] = fmaf(xv1.z, wv.z, acc1[ff]);
                acc1[ff] = fmaf(xv1.w, wv.w, acc1[ff]);
            }
        }
        float* ps = &Pscr[ks][(bp * 16 + fg) * 13];
#pragma unroll
        for (int ff = 0; ff < 6; ++ff) { ps[ff] = acc0[ff]; ps[6 + ff] = acc1[ff]; }
    }
    __syncthreads();

#pragma unroll
    for (int k = 0; k < 3; ++k) {
        const int o = k * 256 + t;          // [0,768) = b*96+f
        const int b = o / 96;
        const int f = o - b * 96;
        const int idx = ((b >> 1) * 16 + (f & 15)) * 13 + (b & 1) * 6 + (f >> 4);
        const float a = Pscr[0][idx] + Pscr[1][idx] + Pscr[2][idx] + Pscr[3][idx];
        G[(size_t)(b0 + b) * 96 + f] = 1.0f / (1.0f + __expf(-BETA * a));
    }
}

// ---------------- K2: contraction (scalar g1 + paired deferred reduce) ----------------
__global__ __launch_bounds__(256, 2) void contract_v8_kernel(
    const float* __restrict__ G,
    const float* __restrict__ V,
    float* __restrict__ out)
{
    __shared__ float Gs[8][100];   // g2/g3 tile
    __shared__ float red[4][8];

    const int t  = threadIdx.x;
    const int b0 = blockIdx.x * 8;

    // V[i][j][4c2..4c2+3] for all i -> 32 float4 regs; coalesced, disjoint per thread
    const float4* V4 = (const float4*)V;
    float4 v[32];
#pragma unroll
    for (int i = 0; i < 32; ++i) v[i] = V4[i * 256 + t];

    // stage G tile (8 rows x 96 = 192 float4), coalesced
    if (t < 192) {
        const float4 gv = ((const float4*)(G + (size_t)b0 * 96))[t];
        const int b   = t / 24;
        const int f4i = t - b * 24;
        *(float4*)&Gs[b][f4i * 4] = gv;
    }
    __syncthreads();

    const int j  = t >> 3;   // [0,32)
    const int c2 = t & 7;    // [0,8)
    const int w  = t >> 6;
    const int l  = t & 63;

    const float* gbase = G + (size_t)b0 * 96;   // wave-uniform base -> s_load path

    // per-b contraction body; g1r indices static after unroll (rule #20 safe)
    auto dotb = [&](const float4* g1r, int b) -> float {
        const float4 g3r = *(const float4*)&Gs[b][64 + c2 * 4];
        const float  g2s = Gs[b][32 + j];
        float ux = 0.f, uy = 0.f, uz = 0.f, uw = 0.f;
#pragma unroll
        for (int i = 0; i < 32; ++i) {
            const float g1i = f4c(g1r[i >> 2], i & 3);
            ux = fmaf(g1i, v[i].x, ux);
            uy = fmaf(g1i, v[i].y, uy);
            uz = fmaf(g1i, v[i].z, uz);
            uw = fmaf(g1i, v[i].w, uw);
        }
        float s = ux * g3r.x;
        s = fmaf(uy, g3r.y, s);
        s = fmaf(uz, g3r.z, s);
        s = fmaf(uw, g3r.w, s);
        return s * g2s;
    };

    float4 gA[8], gB[8];
#pragma unroll
    for (int c = 0; c < 8; ++c) gA[c] = ((const float4*)gbase)[c];   // b=0

    for (int bb = 0; bb < 4; ++bb) {       // runtime loop; all reg indices static inside
        // prefetch odd row 2bb+1 (uniform)
#pragma unroll
        for (int c = 0; c < 8; ++c)
            gB[c] = ((const float4*)(gbase + (size_t)(2 * bb + 1) * 96))[c];

        float pA = dotb(gA, 2 * bb);

        // prefetch next even row 2bb+2 (uniform) before computing with gB
        if (bb < 3) {
#pragma unroll
            for (int c = 0; c < 8; ++c)
                gA[c] = ((const float4*)(gbase + (size_t)(2 * bb + 2) * 96))[c];
        }

        float pB = dotb(gB, 2 * bb + 1);

        // two independent 6-level chains, interleaved (2-way ILP on swizzle latency)
        pA += __shfl_xor(pA, 1);   pB += __shfl_xor(pB, 1);
        pA += __shfl_xor(pA, 2);   pB += __shfl_xor(pB, 2);
        pA += __shfl_xor(pA, 4);   pB += __shfl_xor(pB, 4);
        pA += __shfl_xor(pA, 8);   pB += __shfl_xor(pB, 8);
        pA += __shfl_xor(pA, 16);  pB += __shfl_xor(pB, 16);
        pA += __shfl_xor(pA, 32);  pB += __shfl_xor(pB, 32);
        if (l == 0) { red[w][2 * bb] = pA; red[w][2 * bb + 1] = pB; }
    }
    __syncthreads();

    if (t < 8) out[b0 + t] = red[0][t] + red[1][t] + red[2][t] + red[3][t];
}

extern "C" void kernel_launch(void* const* d_in, const int* in_sizes, int n_in,
                              void* d_out, int out_size, void* d_ws, size_t ws_size,
                              hipStream_t stream) {
    const float* x  = (const float*)d_in[0];
    const float* W1 = (const float*)d_in[1];
    const float* W2 = (const float*)d_in[2];
    const float* W3 = (const float*)d_in[3];
    const float* V  = (const float*)d_in[4];
    float* out = (float*)d_out;
    float* G   = (float*)d_ws;   // 4096*96*4 = 1.5 MB scratch

    gates_v8_kernel<<<dim3(512), dim3(256), 0, stream>>>(x, W1, W2, W3, G);
    contract_v8_kernel<<<dim3(512), dim3(256), 0, stream>>>(G, V, out);
}

// Round 11
// 21.645 us; speedup vs baseline: 1.1132x; 1.1132x over previous
//
#include <hip/hip_runtime.h>

// DLGN_VT v9 — best-of recombination:
//   K1 = v7 gates (lane=batch-row, W via wave-uniform scalar-path reads, NO LDS W):
//     block=(bg:64 rows, fq:12 features), wave=k-quarter; x-quarter in 32 VGPRs;
//     k-partials combined in padded LDS; coalesced G store.
//   K2 = v6 contract (best known): V in 32 float4 regs, thread=(j=t>>3,c2=t&7),
//     g1 via 8 uniform-broadcast LDS b128 reads per b, i-first u4, shfl_xor reduce.
// No atomics, no memset; G (1.5 MB) in d_ws.

#define BETA 30.0f

__device__ __forceinline__ float f4c(const float4 v, int c) {
    // compile-time c after full unroll -> folds to a register pick
    return c == 0 ? v.x : (c == 1 ? v.y : (c == 2 ? v.z : v.w));
}

// ---------------- K1: gates (v7 verbatim) ----------------
__global__ __launch_bounds__(256, 2) void gates_v9_kernel(
    const float* __restrict__ x,
    const float* __restrict__ W1,
    const float* __restrict__ W2,
    const float* __restrict__ W3,
    float* __restrict__ G)
{
    __shared__ float Pscr[4][64 * 13];   // 13312 B; stride 13 -> conflict-free

    const int t    = threadIdx.x;
    const int lane = t & 63;
    const int wv   = __builtin_amdgcn_readfirstlane(t >> 6);   // k-quarter, wave-uniform
    const int bid  = blockIdx.x;          // 512 blocks
    const int bg   = bid >> 3;            // [0,64)
    const int fq   = bid & 7;             // [0,8) -> features fq*12 .. fq*12+11
    const int b0   = bg * 64;
    const int fb   = fq * 12;

    // x quarter for this lane's row -> 32 VGPRs (per-lane gather; x is L2/L3-resident)
    const float4* xrow = (const float4*)(x + (size_t)(b0 + lane) * 128 + wv * 32);
    float xr[32];
#pragma unroll
    for (int c = 0; c < 8; ++c) {
        const float4 xv = xrow[c];
        xr[4 * c + 0] = xv.x; xr[4 * c + 1] = xv.y;
        xr[4 * c + 2] = xv.z; xr[4 * c + 3] = xv.w;
    }

    // 12 features: W pointer wave-uniform -> scalar-path loads feed v_fma(sgpr,vgpr,vgpr)
    float acc[12];
#pragma unroll
    for (int fl = 0; fl < 12; ++fl) {
        const int f = fb + fl;            // runtime but wave-uniform
        const float* Wr = (f < 32) ? (W1 + f * 128)
                        : (f < 64) ? (W2 + (f - 32) * 128)
                                   : (W3 + (f - 64) * 128);
        const float* wq = Wr + wv * 32;   // uniform
        float a = 0.f;
#pragma unroll
        for (int c = 0; c < 32; ++c)
            a = fmaf(wq[c], xr[c], a);
        acc[fl] = a;
    }

    // combine 4 k-quarters in LDS
    float* ps = &Pscr[wv][lane * 13];
#pragma unroll
    for (int fl = 0; fl < 12; ++fl) ps[fl] = acc[fl];
    __syncthreads();

    // 64 b x 12 f = 768 outputs, 3 per thread; coalesced G writes (12-float runs)
#pragma unroll
    for (int q = 0; q < 3; ++q) {
        const int o  = q * 256 + t;       // [0,768)
        const int b  = o / 12;
        const int fl = o - b * 12;
        const float a = Pscr[0][b * 13 + fl] + Pscr[1][b * 13 + fl]
                      + Pscr[2][b * 13 + fl] + Pscr[3][b * 13 + fl];
        G[(size_t)(b0 + b) * 96 + fb + fl] = 1.0f / (1.0f + __expf(-BETA * a));
    }
}

// ---------------- K2: contraction (v6 verbatim) ----------------
__global__ __launch_bounds__(256, 2) void contract_v9_kernel(
    const float* __restrict__ G,
    const float* __restrict__ V,
    float* __restrict__ out)
{
    __shared__ float Gs[8][100];   // 3200 B
    __shared__ float red[4][8];

    const int t  = threadIdx.x;
    const int b0 = blockIdx.x * 8;

    // V[i][j][4c2..4c2+3] for all i -> 32 float4 regs; coalesced, disjoint per thread
    const float4* V4 = (const float4*)V;
    float4 v[32];
#pragma unroll
    for (int i = 0; i < 32; ++i) v[i] = V4[i * 256 + t];

    // stage G tile (8 rows x 96 = 192 float4), coalesced
    if (t < 192) {
        const float4 gv = ((const float4*)(G + (size_t)b0 * 96))[t];
        const int b   = t / 24;          // 24 float4 per row
        const int f4i = t - b * 24;
        *(float4*)&Gs[b][f4i * 4] = gv;
    }
    __syncthreads();

    const int j  = t >> 3;   // [0,32)
    const int c2 = t & 7;    // [0,8)
    const int w  = t >> 6;
    const int l  = t & 63;

    for (int b = 0; b < 8; ++b) {          // runtime loop: regs recycle, no hoist-spill
        const float4* Gr = (const float4*)&Gs[b][0];
        float4 g1r[8];
#pragma unroll
        for (int c = 0; c < 8; ++c) g1r[c] = Gr[c];             // uniform broadcast
        const float4 g3r = *(const float4*)&Gs[b][64 + c2 * 4];
        const float  g2s = Gs[b][32 + j];

        // i-first: u4 = sum_i g1[i] * v[i]  (128 FMA), then dot4 with g3, scale
        float ux = 0.f, uy = 0.f, uz = 0.f, uw = 0.f;
#pragma unroll
        for (int i = 0; i < 32; ++i) {
            const float g1i = f4c(g1r[i >> 2], i & 3);
            ux = fmaf(g1i, v[i].x, ux);
            uy = fmaf(g1i, v[i].y, uy);
            uz = fmaf(g1i, v[i].z, uz);
            uw = fmaf(g1i, v[i].w, uw);
        }
        float s = ux * g3r.x;
        s = fmaf(uy, g3r.y, s);
        s = fmaf(uz, g3r.z, s);
        s = fmaf(uw, g3r.w, s);
        float p = s * g2s;

        p += __shfl_xor(p, 1);
        p += __shfl_xor(p, 2);
        p += __shfl_xor(p, 4);
        p += __shfl_xor(p, 8);
        p += __shfl_xor(p, 16);
        p += __shfl_xor(p, 32);
        if (l == 0) red[w][b] = p;
    }
    __syncthreads();

    if (t < 8) out[b0 + t] = red[0][t] + red[1][t] + red[2][t] + red[3][t];
}

extern "C" void kernel_launch(void* const* d_in, const int* in_sizes, int n_in,
                              void* d_out, int out_size, void* d_ws, size_t ws_size,
                              hipStream_t stream) {
    const float* x  = (const float*)d_in[0];
    const float* W1 = (const float*)d_in[1];
    const float* W2 = (const float*)d_in[2];
    const float* W3 = (const float*)d_in[3];
    const float* V  = (const float*)d_in[4];
    float* out = (float*)d_out;
    float* G   = (float*)d_ws;   // 4096*96*4 = 1.5 MB scratch

    gates_v9_kernel<<<dim3(512), dim3(256), 0, stream>>>(x, W1, W2, W3, G);
    contract_v9_kernel<<<dim3(512), dim3(256), 0, stream>>>(G, V, out);
}

// Round 12
// 16.538 us; speedup vs baseline: 1.4571x; 1.3088x over previous
//
#include <hip/hip_runtime.h>

// DLGN_VT v10 — v6's two proven kernels fused into ONE dispatch:
//   512 blocks x 256 thr, 8 batch rows/block, 2 blocks/CU (LDS 71.5 KB).
//   1. Stage W(96x128)+x(8x128) -> LDS (stride 132).
//   2. Issue all 32 V float4 loads (coalesced, disjoint) -> complete under phase 1.
//   3. Phase 1 (= v6-K1): all 4 waves, k-quarter split, 2-row x 6-feature tile,
//      partials -> Pscr (stride 13), combine+sigmoid -> Gs in LDS (no G round-trip).
//   4. Phase 2 (= v6-K2): thread=(j=t>>3,c2=t&7), i-first u4 with g1 from Gs,
//      shfl_xor reduce -> out.
// No atomics, no memset, no global scratch.

#define BETA 30.0f

__device__ __forceinline__ float f4c(const float4 v, int c) {
    // compile-time c after full unroll -> folds to a register pick
    return c == 0 ? v.x : (c == 1 ? v.y : (c == 2 ? v.z : v.w));
}

__global__ __launch_bounds__(256, 2) void dlgn_v10_kernel(
    const float* __restrict__ x,
    const float* __restrict__ W1,
    const float* __restrict__ W2,
    const float* __restrict__ W3,
    const float* __restrict__ V,
    float* __restrict__ out)
{
    __shared__ float Wlds[96 * 132];    // 50688 B
    __shared__ float xlds[8 * 132];     //  4224 B
    __shared__ float Pscr[4][64 * 13];  // 13312 B
    __shared__ float Gs[8][100];        //  3200 B
    __shared__ float red[4][8];         //   128 B   -> 71552 B total (2 blocks/CU)

    const int t  = threadIdx.x;
    const int b0 = blockIdx.x * 8;

    // ---- Stage W rows 0..95 + x rows 96..103 : 3328 float4 = 13/thread, coalesced ----
#pragma unroll
    for (int r = 0; r < 13; ++r) {
        const int idx  = r * 256 + t;
        const int row  = idx >> 5;
        const int col4 = idx & 31;
        if (row < 96) {
            const float* Wr = (row < 32) ? (W1 + row * 128)
                            : (row < 64) ? (W2 + (row - 32) * 128)
                                         : (W3 + (row - 64) * 128);
            *(float4*)&Wlds[row * 132 + col4 * 4] = ((const float4*)Wr)[col4];
        } else {
            *(float4*)&xlds[(row - 96) * 132 + col4 * 4] =
                ((const float4*)(x + (size_t)(b0 + row - 96) * 128))[col4];
        }
    }

    // ---- Issue V loads now; they complete under phase 1 ----
    const float4* V4 = (const float4*)V;   // f4 idx = i*256 + (j*8 + c2) = i*256 + t
    float4 v[32];
#pragma unroll
    for (int i = 0; i < 32; ++i) v[i] = V4[i * 256 + t];

    __syncthreads();

    // ---- Phase 1 (v6-K1): all 4 waves, ks = k-quarter; bp = row pair; fg ----
    {
        const int ks  = t >> 6;
        const int sub = t & 63;
        const int bp  = sub & 3;
        const int fg  = sub >> 2;          // 0..15, f = fg + 16*ff
        const float* xr0 = &xlds[(2 * bp + 0) * 132];
        const float* xr1 = &xlds[(2 * bp + 1) * 132];
        const float* wb  = &Wlds[fg * 132];
        float acc0[6] = {0.f,0.f,0.f,0.f,0.f,0.f};
        float acc1[6] = {0.f,0.f,0.f,0.f,0.f,0.f};
#pragma unroll
        for (int cc = 0; cc < 8; ++cc) {
            const int c4 = (ks * 8 + cc) * 4;
            const float4 xv0 = *(const float4*)&xr0[c4];
            const float4 xv1 = *(const float4*)&xr1[c4];
#pragma unroll
            for (int ff = 0; ff < 6; ++ff) {
                const float4 wv = *(const float4*)&wb[ff * 2112 + c4];  // row fg+16ff
                acc0[ff] = fmaf(xv0.x, wv.x, acc0[ff]);
                acc0[ff] = fmaf(xv0.y, wv.y, acc0[ff]);
                acc0[ff] = fmaf(xv0.z, wv.z, acc0[ff]);
                acc0[ff] = fmaf(xv0.w, wv.w, acc0[ff]);
                acc1[ff] = fmaf(xv1.x, wv.x, acc1[ff]);
                acc1[ff] = fmaf(xv1.y, wv.y, acc1[ff]);
                acc1[ff] = fmaf(xv1.z, wv.z, acc1[ff]);
                acc1[ff] = fmaf(xv1.w, wv.w, acc1[ff]);
            }
        }
        float* ps = &Pscr[ks][(bp * 16 + fg) * 13];
#pragma unroll
        for (int ff = 0; ff < 6; ++ff) { ps[ff] = acc0[ff]; ps[6 + ff] = acc1[ff]; }
    }
    __syncthreads();

    // ---- Combine 4 k-quarters + sigmoid -> Gs (LDS, no global round-trip) ----
#pragma unroll
    for (int k = 0; k < 3; ++k) {
        const int o = k * 256 + t;          // [0,768) = b*96+f
        const int b = o / 96;
        const int f = o - b * 96;
        const int idx = ((b >> 1) * 16 + (f & 15)) * 13 + (b & 1) * 6 + (f >> 4);
        const float a = Pscr[0][idx] + Pscr[1][idx] + Pscr[2][idx] + Pscr[3][idx];
        Gs[b][f] = 1.0f / (1.0f + __expf(-BETA * a));
    }
    __syncthreads();

    // ---- Phase 2 (v6-K2): thread = (j = t>>3, c2 = t&7); V already in regs ----
    const int j  = t >> 3;   // [0,32)
    const int c2 = t & 7;    // [0,8)
    const int w  = t >> 6;
    const int l  = t & 63;

    for (int b = 0; b < 8; ++b) {          // runtime loop: regs recycle, no hoist-spill
        const float4* Gr = (const float4*)&Gs[b][0];
        float4 g1r[8];
#pragma unroll
        for (int c = 0; c < 8; ++c) g1r[c] = Gr[c];             // uniform broadcast
        const float4 g3r = *(const float4*)&Gs[b][64 + c2 * 4]; // 8 addrs, 32 banks
        const float  g2s = Gs[b][32 + j];                       // 2-way (free)

        // i-first: u4 = sum_i g1[i] * v[i]  (128 FMA), then dot4 with g3, scale
        float ux = 0.f, uy = 0.f, uz = 0.f, uw = 0.f;
#pragma unroll
        for (int i = 0; i < 32; ++i) {
            const float g1i = f4c(g1r[i >> 2], i & 3);
            ux = fmaf(g1i, v[i].x, ux);
            uy = fmaf(g1i, v[i].y, uy);
            uz = fmaf(g1i, v[i].z, uz);
            uw = fmaf(g1i, v[i].w, uw);
        }
        float s = ux * g3r.x;
        s = fmaf(uy, g3r.y, s);
        s = fmaf(uz, g3r.z, s);
        s = fmaf(uw, g3r.w, s);
        float p = s * g2s;

        p += __shfl_xor(p, 1);
        p += __shfl_xor(p, 2);
        p += __shfl_xor(p, 4);
        p += __shfl_xor(p, 8);
        p += __shfl_xor(p, 16);
        p += __shfl_xor(p, 32);
        if (l == 0) red[w][b] = p;
    }
    __syncthreads();

    if (t < 8) out[b0 + t] = red[0][t] + red[1][t] + red[2][t] + red[3][t];
}

extern "C" void kernel_launch(void* const* d_in, const int* in_sizes, int n_in,
                              void* d_out, int out_size, void* d_ws, size_t ws_size,
                              hipStream_t stream) {
    const float* x  = (const float*)d_in[0];
    const float* W1 = (const float*)d_in[1];
    const float* W2 = (const float*)d_in[2];
    const float* W3 = (const float*)d_in[3];
    const float* V  = (const float*)d_in[4];
    float* out = (float*)d_out;

    dlgn_v10_kernel<<<dim3(512), dim3(256), 0, stream>>>(x, W1, W2, W3, V, out);
}

// Round 13
// 15.204 us; speedup vs baseline: 1.5849x; 1.0877x over previous
//
#include <hip/hip_runtime.h>

// DLGN_VT v11 — fused, phase-1 de-LDS'd:
//   512 blocks x 256 thr, 8 batch rows/block. LDS only 8.5 KB (x tile + Gs + red).
//   Thread (fl = t>>3, kc = t&7) holds W1/W2/W3[fl][16kc..+15] in 48 regs (coalesced
//   global loads, L2-resident). x staged in LDS with kc-skew (stride-20 chunks,
//   conflict-free broadcast). Per row: 4 x b128 reads -> 48 FMA (3 matrices).
//   k-eighth partials combined via shfl_xor(1,2,4); row-select; sigmoid -> Gs.
//   V loads issued after FMA loop (W regs dead) -> latency hides under combine.
//   Phase 2 = v6-K2: V in 32 float4 regs, thread=(j,c2), i-first u4, shfl reduce.
// No atomics, no memset, no global scratch, 3 barriers.

#define BETA 30.0f

__device__ __forceinline__ float f4c(const float4 v, int c) {
    // compile-time c after full unroll -> folds to a register pick
    return c == 0 ? v.x : (c == 1 ? v.y : (c == 2 ? v.z : v.w));
}

__global__ __launch_bounds__(256, 2) void dlgn_v11_kernel(
    const float* __restrict__ x,
    const float* __restrict__ W1,
    const float* __restrict__ W2,
    const float* __restrict__ W3,
    const float* __restrict__ V,
    float* __restrict__ out)
{
    __shared__ float xlds[8 * 160];   // 5120 B: row stride 160, kc-chunk stride 20
    __shared__ float Gs[8][100];      // 3200 B
    __shared__ float red[4][8];       //  128 B

    const int t  = threadIdx.x;
    const int b0 = blockIdx.x * 8;

    // ---- Stage x tile: 8 rows x 32 float4 = 1/thread, coalesced; kc-skewed layout ----
    {
        const int r    = t >> 5;
        const int col4 = t & 31;
        const float4 xv = ((const float4*)(x + (size_t)(b0 + r) * 128))[col4];
        const int skc = col4 >> 2, sc = col4 & 3;
        *(float4*)&xlds[r * 160 + skc * 20 + sc * 4] = xv;
    }

    // ---- W chunks -> 48 registers (global, L2-resident; overlaps x staging) ----
    const int fl = t >> 3;   // feature-lane 0..31
    const int kc = t & 7;    // k-chunk 0..7 (16 floats each)
    float4 w1c[4], w2c[4], w3c[4];
    {
        const float4* W1r = (const float4*)(W1 + fl * 128 + kc * 16);
        const float4* W2r = (const float4*)(W2 + fl * 128 + kc * 16);
        const float4* W3r = (const float4*)(W3 + fl * 128 + kc * 16);
#pragma unroll
        for (int c = 0; c < 4; ++c) {
            w1c[c] = W1r[c]; w2c[c] = W2r[c]; w3c[c] = W3r[c];
        }
    }
    __syncthreads();   // xlds ready

    // ---- Phase 1: 8 rows x 3 matrices, k-eighth partial dots ----
    float acc[3][8];
#pragma unroll
    for (int m = 0; m < 3; ++m)
#pragma unroll
        for (int r = 0; r < 8; ++r) acc[m][r] = 0.f;

#pragma unroll
    for (int r = 0; r < 8; ++r) {
        float4 xc[4];
#pragma unroll
        for (int c = 0; c < 4; ++c)
            xc[c] = *(const float4*)&xlds[r * 160 + kc * 20 + c * 4];
#pragma unroll
        for (int c = 0; c < 4; ++c) {
            acc[0][r] = fmaf(w1c[c].x, xc[c].x, acc[0][r]);
            acc[0][r] = fmaf(w1c[c].y, xc[c].y, acc[0][r]);
            acc[0][r] = fmaf(w1c[c].z, xc[c].z, acc[0][r]);
            acc[0][r] = fmaf(w1c[c].w, xc[c].w, acc[0][r]);
            acc[1][r] = fmaf(w2c[c].x, xc[c].x, acc[1][r]);
            acc[1][r] = fmaf(w2c[c].y, xc[c].y, acc[1][r]);
            acc[1][r] = fmaf(w2c[c].z, xc[c].z, acc[1][r]);
            acc[1][r] = fmaf(w2c[c].w, xc[c].w, acc[1][r]);
            acc[2][r] = fmaf(w3c[c].x, xc[c].x, acc[2][r]);
            acc[2][r] = fmaf(w3c[c].y, xc[c].y, acc[2][r]);
            acc[2][r] = fmaf(w3c[c].z, xc[c].z, acc[2][r]);
            acc[2][r] = fmaf(w3c[c].w, xc[c].w, acc[2][r]);
        }
    }

    // ---- Issue V loads now (W regs dead); complete under combine + barrier ----
    const float4* V4 = (const float4*)V;   // f4 idx = i*256 + t
    float4 v[32];
#pragma unroll
    for (int i = 0; i < 32; ++i) v[i] = V4[i * 256 + t];

    // ---- Combine k-eighths via shfl_xor over kc bits; select row kc; sigmoid -> Gs ----
#pragma unroll
    for (int m = 0; m < 3; ++m) {
        float sel = 0.f;
#pragma unroll
        for (int r = 0; r < 8; ++r) {
            float a = acc[m][r];
            a += __shfl_xor(a, 1);
            a += __shfl_xor(a, 2);
            a += __shfl_xor(a, 4);
            if (kc == r) sel = a;      // unrolled select chain (static indices)
        }
        // thread writes gate (row = kc, feature = 32m + fl); <=2-way banks
        Gs[kc][32 * m + fl] = 1.0f / (1.0f + __expf(-BETA * sel));
    }
    __syncthreads();

    // ---- Phase 2 (v6-K2): thread = (j = t>>3, c2 = t&7); V already in regs ----
    const int j  = t >> 3;   // [0,32)
    const int c2 = t & 7;    // [0,8)
    const int w  = t >> 6;
    const int l  = t & 63;

    for (int b = 0; b < 8; ++b) {          // runtime loop: regs recycle, no hoist-spill
        const float4* Gr = (const float4*)&Gs[b][0];
        float4 g1r[8];
#pragma unroll
        for (int c = 0; c < 8; ++c) g1r[c] = Gr[c];             // uniform broadcast
        const float4 g3r = *(const float4*)&Gs[b][64 + c2 * 4];
        const float  g2s = Gs[b][32 + j];

        // i-first: u4 = sum_i g1[i] * v[i]  (128 FMA), then dot4 with g3, scale
        float ux = 0.f, uy = 0.f, uz = 0.f, uw = 0.f;
#pragma unroll
        for (int i = 0; i < 32; ++i) {
            const float g1i = f4c(g1r[i >> 2], i & 3);
            ux = fmaf(g1i, v[i].x, ux);
            uy = fmaf(g1i, v[i].y, uy);
            uz = fmaf(g1i, v[i].z, uz);
            uw = fmaf(g1i, v[i].w, uw);
        }
        float s = ux * g3r.x;
        s = fmaf(uy, g3r.y, s);
        s = fmaf(uz, g3r.z, s);
        s = fmaf(uw, g3r.w, s);
        float p = s * g2s;

        p += __shfl_xor(p, 1);
        p += __shfl_xor(p, 2);
        p += __shfl_xor(p, 4);
        p += __shfl_xor(p, 8);
        p += __shfl_xor(p, 16);
        p += __shfl_xor(p, 32);
        if (l == 0) red[w][b] = p;
    }
    __syncthreads();

    if (t < 8) out[b0 + t] = red[0][t] + red[1][t] + red[2][t] + red[3][t];
}

extern "C" void kernel_launch(void* const* d_in, const int* in_sizes, int n_in,
                              void* d_out, int out_size, void* d_ws, size_t ws_size,
                              hipStream_t stream) {
    const float* x  = (const float*)d_in[0];
    const float* W1 = (const float*)d_in[1];
    const float* W2 = (const float*)d_in[2];
    const float* W3 = (const float*)d_in[3];
    const float* V  = (const float*)d_in[4];
    float* out = (float*)d_out;

    dlgn_v11_kernel<<<dim3(512), dim3(256), 0, stream>>>(x, W1, W2, W3, V, out);
}

// Round 14
// 13.968 us; speedup vs baseline: 1.7251x; 1.0885x over previous
//
#include <hip/hip_runtime.h>

// DLGN_VT v12 — fused, LDS-instruction diet:
//   512 blocks x 256 thr, 8 rows/block, launch_bounds(256,2). LDS 18.6 KB.
//   Phase 1 (= v11): thread (fl=t>>3, kc=t&7) holds W1/2/3 chunks in 48 regs;
//     x kc-skewed in LDS; 8 rows x 48 FMA; combine k-eighths with DPP quad_perm
//     (xor1,xor2 on VALU) + one ds_swizzle (xor4); sigmoid -> Gs[8][100].
//   V loads issued after phase-1 FMA (W regs dead).
//   Phase 2: per b (FULLY unrolled): ONE ds_read_b32 spreads g1 over lanes 0..31,
//     g1[i] = v_readlane(ga, i) -> SGPR operand of v_fma; g2 b32 + g3 b128 reads;
//     i-first u4; p8[b] accumulated in regs.
//   Reduce: pack p8 -> 2 ds_write_b128 (stride-10 pad), barrier, final pass
//     8 b32 reads + 5 shfl_xor -> out.
// No atomics, no memset, no global scratch.

#define BETA 30.0f

__device__ __forceinline__ float f4c(const float4 v, int c) {
    return c == 0 ? v.x : (c == 1 ? v.y : (c == 2 ? v.z : v.w));
}

// quad_perm DPP: full row/bank mask, bound_ctrl=1 -> old-value-independent
__device__ __forceinline__ float qp_xor1(float a) {   // [1,0,3,2] = 0xB1
    return __int_as_float(__builtin_amdgcn_mov_dpp(__float_as_int(a), 0xB1, 0xF, 0xF, true));
}
__device__ __forceinline__ float qp_xor2(float a) {   // [2,3,0,1] = 0x4E
    return __int_as_float(__builtin_amdgcn_mov_dpp(__float_as_int(a), 0x4E, 0xF, 0xF, true));
}

__global__ __launch_bounds__(256, 2) void dlgn_v12_kernel(
    const float* __restrict__ x,
    const float* __restrict__ W1,
    const float* __restrict__ W2,
    const float* __restrict__ W3,
    const float* __restrict__ V,
    float* __restrict__ out)
{
    __shared__ float xlds[8 * 160];   // 5120 B: kc-chunk stride 20
    __shared__ float Gs[8][100];      // 3200 B
    __shared__ float Plds[2560];      // 10240 B: per-thread stride 10 (b128-aligned)

    const int t  = threadIdx.x;
    const int b0 = blockIdx.x * 8;

    // ---- Stage x tile: 1 float4/thread, coalesced; kc-skewed layout ----
    {
        const int r    = t >> 5;
        const int col4 = t & 31;
        const float4 xv = ((const float4*)(x + (size_t)(b0 + r) * 128))[col4];
        const int skc = col4 >> 2, sc = col4 & 3;
        *(float4*)&xlds[r * 160 + skc * 20 + sc * 4] = xv;
    }

    // ---- W chunks -> 48 registers (global, L2-resident) ----
    const int fl = t >> 3;   // feature-lane 0..31
    const int kc = t & 7;    // k-chunk 0..7
    float4 w1c[4], w2c[4], w3c[4];
    {
        const float4* W1r = (const float4*)(W1 + fl * 128 + kc * 16);
        const float4* W2r = (const float4*)(W2 + fl * 128 + kc * 16);
        const float4* W3r = (const float4*)(W3 + fl * 128 + kc * 16);
#pragma unroll
        for (int c = 0; c < 4; ++c) {
            w1c[c] = W1r[c]; w2c[c] = W2r[c]; w3c[c] = W3r[c];
        }
    }
    __syncthreads();   // xlds ready

    // ---- Phase 1: 8 rows x 3 matrices, k-eighth partial dots ----
    float acc[3][8];
#pragma unroll
    for (int m = 0; m < 3; ++m)
#pragma unroll
        for (int r = 0; r < 8; ++r) acc[m][r] = 0.f;

#pragma unroll
    for (int r = 0; r < 8; ++r) {
        float4 xc[4];
#pragma unroll
        for (int c = 0; c < 4; ++c)
            xc[c] = *(const float4*)&xlds[r * 160 + kc * 20 + c * 4];
#pragma unroll
        for (int c = 0; c < 4; ++c) {
            acc[0][r] = fmaf(w1c[c].x, xc[c].x, acc[0][r]);
            acc[0][r] = fmaf(w1c[c].y, xc[c].y, acc[0][r]);
            acc[0][r] = fmaf(w1c[c].z, xc[c].z, acc[0][r]);
            acc[0][r] = fmaf(w1c[c].w, xc[c].w, acc[0][r]);
            acc[1][r] = fmaf(w2c[c].x, xc[c].x, acc[1][r]);
            acc[1][r] = fmaf(w2c[c].y, xc[c].y, acc[1][r]);
            acc[1][r] = fmaf(w2c[c].z, xc[c].z, acc[1][r]);
            acc[1][r] = fmaf(w2c[c].w, xc[c].w, acc[1][r]);
            acc[2][r] = fmaf(w3c[c].x, xc[c].x, acc[2][r]);
            acc[2][r] = fmaf(w3c[c].y, xc[c].y, acc[2][r]);
            acc[2][r] = fmaf(w3c[c].z, xc[c].z, acc[2][r]);
            acc[2][r] = fmaf(w3c[c].w, xc[c].w, acc[2][r]);
        }
    }

    // ---- Issue V loads now (W regs dead); complete under combine + barrier ----
    const float4* V4 = (const float4*)V;   // f4 idx = i*256 + t
    float4 v[32];
#pragma unroll
    for (int i = 0; i < 32; ++i) v[i] = V4[i * 256 + t];

    // ---- Combine k-eighths: xor1,xor2 on VALU (DPP), xor4 via shfl; sigmoid -> Gs ----
#pragma unroll
    for (int m = 0; m < 3; ++m) {
        float sel = 0.f;
#pragma unroll
        for (int r = 0; r < 8; ++r) {
            float a = acc[m][r];
            a += qp_xor1(a);
            a += qp_xor2(a);
            a += __shfl_xor(a, 4);
            if (kc == r) sel = a;      // static select chain
        }
        Gs[kc][32 * m + fl] = 1.0f / (1.0f + __expf(-BETA * sel));
    }
    __syncthreads();

    // ---- Phase 2: thread = (j = t>>3, c2 = t&7); g1 via readlane ----
    const int j  = t >> 3;   // [0,32)
    const int c2 = t & 7;    // [0,8)

    float p8[8];
#pragma unroll
    for (int b = 0; b < 8; ++b) {
        const float  ga  = Gs[b][t & 31];               // lane i holds g1[b][i] (i=lane&31)
        const float  g2s = Gs[b][32 + j];               // 8 banks, broadcast
        const float4 g3r = *(const float4*)&Gs[b][64 + c2 * 4];

        float ux = 0.f, uy = 0.f, uz = 0.f, uw = 0.f;
#pragma unroll
        for (int i = 0; i < 32; ++i) {
            const float g1i = __int_as_float(
                __builtin_amdgcn_readlane(__float_as_int(ga), i));   // SGPR
            ux = fmaf(g1i, v[i].x, ux);
            uy = fmaf(g1i, v[i].y, uy);
            uz = fmaf(g1i, v[i].z, uz);
            uw = fmaf(g1i, v[i].w, uw);
        }
        float s = ux * g3r.x;
        s = fmaf(uy, g3r.y, s);
        s = fmaf(uz, g3r.z, s);
        s = fmaf(uw, g3r.w, s);
        p8[b] = s * g2s;
    }

    // ---- Deferred reduction: 2 packed b128 writes, barrier, one final pass ----
    *(float4*)&Plds[t * 10]     = make_float4(p8[0], p8[1], p8[2], p8[3]);
    *(float4*)&Plds[t * 10 + 4] = make_float4(p8[4], p8[5], p8[6], p8[7]);
    __syncthreads();

    {
        const int fb2 = t >> 5;   // b index 0..7
        const int pt  = t & 31;   // partial index
        float s = 0.f;
#pragma unroll
        for (int s8 = 0; s8 < 8; ++s8)
            s += Plds[(pt + s8 * 32) * 10 + fb2];
        s += __shfl_xor(s, 1);
        s += __shfl_xor(s, 2);
        s += __shfl_xor(s, 4);
        s += __shfl_xor(s, 8);
        s += __shfl_xor(s, 16);
        if (pt == 0) out[b0 + fb2] = s;
    }
}

extern "C" void kernel_launch(void* const* d_in, const int* in_sizes, int n_in,
                              void* d_out, int out_size, void* d_ws, size_t ws_size,
                              hipStream_t stream) {
    const float* x  = (const float*)d_in[0];
    const float* W1 = (const float*)d_in[1];
    const float* W2 = (const float*)d_in[2];
    const float* W3 = (const float*)d_in[3];
    const float* V  = (const float*)d_in[4];
    float* out = (float*)d_out;

    dlgn_v12_kernel<<<dim3(512), dim3(256), 0, stream>>>(x, W1, W2, W3, V, out);
}